// Round 4
// baseline (203.397 us; speedup 1.0000x reference)
//
#include <hip/hip_runtime.h>
#include <math.h>

// GAUSConv: ft = bf16(feat@W.T) via MFMA -> bucket-radix edge pass -> per-bucket
// fused gaussian-softmax-reduce (softmax identity: out = sum(w*ft_src)/sum(w) + bias).
// Round-11: occupancy attack.
//  - fused_node __launch_bounds__(256,8): round-10 VGPR=60 fits the 64 cap; grid
//    (6.1 blocks/CU) now fully resident -> 24 waves/CU vs 16. Gather-latency loop
//    has ~25% per-wave issue duty -> more waves = direct time cut.
//  - produce GEMM epilogue: stage 64x128 bf16 tile in LDS (stride 132, quad bank
//    sets disjoint), write ftb as coalesced 16B stores (was: 32 scattered 2B
//    global stores per lane). LDS overlays the scatter path's 24KB (union).
// N=50000, E=800000, D=128, K=4, F=32 (K*F = 128 = D)
#define N_NODES 50000
#define NROWS   50001          // +1 sentinel row (index 50000)
#define DUMMY   50000
#define N_EDGES 800000
#define NBUCKET 1563           // ceil(50000/32) coarse buckets, dst>>5
#define NB_POW  2048           // counter array size (pow2 >= NBUCKET)
#define CAP     704            // per-bucket pool capacity (mean 512, +8 sigma)
#define BIN     64             // per-dst cap; max in-degree ~35 for Poisson(16)
#define SPAD    72             // s_src row stride (u16): 144B, 16B-aligned rows
#define TSTR    132            // GEMM LDS tile row stride (u16): quad bank sets disjoint
#define SC_BLOCKS 196          // ceil(800000/4096) scatter blocks, 4096 edges each
#define GEMM_BLOCKS 782        // 64 rows each
#define SENT 0xFFFFFFFFu
#define DPAT 0xC350C350u       // u16 pattern = 50000 (sentinel)
#define DVAL 0x4E6Eu           // bf16 ~9.96e8: q ~ 3e19, sqrt ~ 5.6e9, w = 0 exactly

typedef __attribute__((ext_vector_type(8))) short bf16x8;
typedef __attribute__((ext_vector_type(4))) float f32x4;
typedef __attribute__((ext_vector_type(2))) float f32x2;
typedef __attribute__((ext_vector_type(8))) float f32x8;

__device__ __forceinline__ unsigned short f2b(float f) {   // fp32 -> bf16 bits, RNE
    union { float f; unsigned u; } v; v.f = f;
    return (unsigned short)((v.u + 0x7FFFu + ((v.u >> 16) & 1u)) >> 16);
}
__device__ __forceinline__ float b2f_lo(unsigned u) {
    union { unsigned u; float f; } v; v.u = u << 16; return v.f;
}
__device__ __forceinline__ float b2f_hi(unsigned u) {
    union { unsigned u; float f; } v; v.u = u & 0xFFFF0000u; return v.f;
}
// decode a dword (2 bf16) into a packed f32 pair {lo_ch, hi_ch}
__device__ __forceinline__ f32x2 b2f2(unsigned u) {
    f32x2 r; r[0] = b2f_lo(u); r[1] = b2f_hi(u); return r;
}
// VOP3P packed f32 math (2 FMAs / 2 ADDs per instruction)
__device__ __forceinline__ f32x2 pk_fma(f32x2 a, f32x2 b, f32x2 c) {
    f32x2 d;
    asm("v_pk_fma_f32 %0, %1, %2, %3" : "=v"(d) : "v"(a), "v"(b), "v"(c));
    return d;
}
__device__ __forceinline__ f32x2 pk_add(f32x2 a, f32x2 b) {
    f32x2 d;
    asm("v_pk_add_f32 %0, %1, %2" : "=v"(d) : "v"(a), "v"(b));
    return d;
}
// q += quad-lane butterfly via DPP (no LDS pipe)
#define DPP_ADD(q, CTRL) { \
    int _r = __builtin_amdgcn_update_dpp(0, __builtin_bit_cast(int, q), CTRL, 0xF, 0xF, false); \
    q += __builtin_bit_cast(float, _r); }

#if __has_builtin(__builtin_amdgcn_exp2f)
#define EXP2F(x) __builtin_amdgcn_exp2f(x)
#else
#define EXP2F(x) exp2f(x)
#endif

// ---------------- prep: W -> bf16 + zero bucket counters + sentinel ft row ----------
__global__ __launch_bounds__(256) void prep(const float* __restrict__ W,
                                            unsigned short* __restrict__ Wb,
                                            int* __restrict__ bcount,
                                            unsigned short* __restrict__ ftb) {
    int idx = blockIdx.x * 256 + threadIdx.x;
    if (idx < 4096) {
        int i = idx * 4;
        float4 v = *(const float4*)(W + i);
        Wb[i + 0] = f2b(v.x); Wb[i + 1] = f2b(v.y);
        Wb[i + 2] = f2b(v.z); Wb[i + 3] = f2b(v.w);
    } else if (idx < 4096 + NB_POW) {
        bcount[idx - 4096] = 0;
    } else if (idx < 4096 + NB_POW + 32) {
        int i = (idx - 4096 - NB_POW) * 4;
        unsigned short* p = ftb + (size_t)DUMMY * 128 + i;
        p[0] = DVAL; p[1] = DVAL; p[2] = DVAL; p[3] = DVAL;
    }
}

// ---------------- produce: [0,SC) bucket scatter || [SC,SC+GEMM) MFMA GEMM ----------
__global__ __launch_bounds__(256) void produce(const float* __restrict__ feat,
                                               const unsigned short* __restrict__ Wb,
                                               unsigned short* __restrict__ ftb,
                                               const int* __restrict__ src,
                                               const int* __restrict__ dst,
                                               int* __restrict__ bcount,
                                               unsigned* __restrict__ pool, int n) {
    __shared__ int smem[3 * NB_POW];     // 24 KB, overlaid: scatter hist | GEMM tile
    if (blockIdx.x < SC_BLOCKS) {
        int* hist = smem;
        int* gbase = smem + NB_POW;
        int* cur = smem + 2 * NB_POW;
        int t = threadIdx.x;
        #pragma unroll
        for (int i = 0; i < NB_POW / 256; ++i) hist[t + i * 256] = 0;
        __syncthreads();

        unsigned key[16];
        int ebase = blockIdx.x * 4096 + (t << 2);
        #pragma unroll
        for (int i = 0; i < 4; ++i) {
            int e = ebase + i * 1024;
            if (e + 3 < N_EDGES) {
                int4 s4 = *(const int4*)(src + e);
                int4 d4 = *(const int4*)(dst + e);
                key[i * 4 + 0] = ((unsigned)d4.x << 16) | (unsigned)s4.x;
                key[i * 4 + 1] = ((unsigned)d4.y << 16) | (unsigned)s4.y;
                key[i * 4 + 2] = ((unsigned)d4.z << 16) | (unsigned)s4.z;
                key[i * 4 + 3] = ((unsigned)d4.w << 16) | (unsigned)s4.w;
            } else {
                #pragma unroll
                for (int j = 0; j < 4; ++j) {
                    int ee = e + j;
                    key[i * 4 + j] = (ee < N_EDGES)
                        ? (((unsigned)dst[ee] << 16) | (unsigned)src[ee]) : SENT;
                }
            }
        }
        #pragma unroll
        for (int i = 0; i < 16; ++i)
            if (key[i] != SENT) atomicAdd(&hist[key[i] >> 21], 1);
        __syncthreads();
        #pragma unroll
        for (int i = 0; i < NB_POW / 256; ++i) {
            int b = t + i * 256;
            int h = hist[b];
            cur[b] = 0;
            gbase[b] = (h > 0) ? atomicAdd(&bcount[b], h) : 0;
        }
        __syncthreads();
        #pragma unroll
        for (int i = 0; i < 16; ++i) {
            unsigned kk = key[i];
            if (kk != SENT) {
                int b = kk >> 21;                     // dst>>5
                int pos = gbase[b] + atomicAdd(&cur[b], 1);
                if (pos < CAP) pool[(size_t)b * CAP + pos] = kk;
            }
        }
        return;
    }
    // ---- GEMM path ----
    int gb = blockIdx.x - SC_BLOCKS;
    int t = threadIdx.x;
    int wave = t >> 6, l = t & 63;
    int m = l & 15, quad = l >> 4;
    int row0 = gb * 64 + wave * 16;
    int grow = row0 + m;
    int arow = grow < n ? grow : (n - 1);
    f32x4 acc[8] = {};
    const float* ap = feat + (size_t)arow * 128 + quad * 8;
    #pragma unroll
    for (int ks = 0; ks < 4; ++ks) {
        float4 a0 = *(const float4*)(ap + ks * 32);
        float4 a1 = *(const float4*)(ap + ks * 32 + 4);
        bf16x8 af;
        af[0] = (short)f2b(a0.x); af[1] = (short)f2b(a0.y);
        af[2] = (short)f2b(a0.z); af[3] = (short)f2b(a0.w);
        af[4] = (short)f2b(a1.x); af[5] = (short)f2b(a1.y);
        af[6] = (short)f2b(a1.z); af[7] = (short)f2b(a1.w);
        #pragma unroll
        for (int ct = 0; ct < 8; ++ct) {
            int ncol = ct * 16 + m;
            bf16x8 bf = *(const bf16x8*)(Wb + (size_t)ncol * 128 + ks * 32 + quad * 8);
            acc[ct] = __builtin_amdgcn_mfma_f32_16x16x32_bf16(af, bf, acc[ct], 0, 0, 0);
        }
    }
    // stage tile in LDS (row stride 132 u16 -> quads hit disjoint bank sets),
    // then write ftb coalesced 16B (was: 32 scattered 2B stores per lane).
    unsigned short* tile = (unsigned short*)smem;   // 64*132*2 = 16.9 KB <= 24 KB
    #pragma unroll
    for (int r = 0; r < 4; ++r) {
        int trow = wave * 16 + quad * 4 + r;
        #pragma unroll
        for (int ct = 0; ct < 8; ++ct)
            tile[trow * TSTR + ct * 16 + m] = f2b(acc[ct][r]);
    }
    __syncthreads();
    #pragma unroll
    for (int it = 0; it < 4; ++it) {
        int elem = (t + it * 256) * 8;   // < 8192
        int row = elem >> 7;
        int col = elem & 127;
        int gr = gb * 64 + row;
        if (gr < n) {
            const unsigned short* tp = tile + row * TSTR + col;
            uint2 lo = *(const uint2*)tp;
            uint2 hi = *(const uint2*)(tp + 4);
            uint4 v = make_uint4(lo.x, lo.y, hi.x, hi.y);
            *(uint4*)(ftb + (size_t)gr * 128 + col) = v;
        }
    }
}

// ---------------- fused: bucket LDS binning + gaussian-softmax-reduce ----------
// consume 4 edges, packed-f32 math, DPP reduce, no masks (sentinel rows -> w=0).
__device__ __forceinline__ void consume4pk(uint4 r0, uint4 r1, uint4 r2, uint4 r3,
                                           const f32x2* nb, float nsig2,
                                           f32x2* acc, float& den) {
    #define EDGE(R) { \
        f32x2 f0 = b2f2(R.x), f1 = b2f2(R.y), f2 = b2f2(R.z), f3 = b2f2(R.w); \
        f32x2 d0 = pk_add(f0, nb[0]), d1 = pk_add(f1, nb[1]); \
        f32x2 d2 = pk_add(f2, nb[2]), d3 = pk_add(f3, nb[3]); \
        f32x2 q2 = pk_fma(d0, d0, pk_fma(d1, d1, pk_fma(d2, d2, pk_fma(d3, d3, (f32x2)(0.f))))); \
        float q = q2[0] + q2[1]; \
        DPP_ADD(q, 0xB1) \
        DPP_ADD(q, 0x4E) \
        float w = EXP2F(nsig2 * __builtin_amdgcn_sqrtf(q)); \
        f32x2 w2; w2[0] = w; w2[1] = w; \
        acc[0] = pk_fma(f0, w2, acc[0]); acc[1] = pk_fma(f1, w2, acc[1]); \
        acc[2] = pk_fma(f2, w2, acc[2]); acc[3] = pk_fma(f3, w2, acc[3]); \
        den += w; }
    EDGE(r0) EDGE(r1) EDGE(r2) EDGE(r3)
    #undef EDGE
}

__global__ __launch_bounds__(256, 8) void fused_node(const unsigned short* __restrict__ ftb,
                                                     const float* __restrict__ mu,
                                                     const float* __restrict__ sigma,
                                                     const int* __restrict__ bcount,
                                                     const unsigned* __restrict__ pool,
                                                     const float* __restrict__ bias,
                                                     float* __restrict__ out, int n) {
    __shared__ __align__(16) unsigned short s_src[32][SPAD];   // 4608 B
    __shared__ int dcnt[32];
    int t = threadIdx.x;
    int b = blockIdx.x;
    {   // sentinel-fill: unused slots gather the dummy row -> w = 0, no masking
        uint4* p = (uint4*)&s_src[0][0];
        const uint4 DP = make_uint4(DPAT, DPAT, DPAT, DPAT);
        for (int i = t; i < 32 * SPAD * 2 / 16; i += 256) p[i] = DP;
    }
    if (t < 32) dcnt[t] = 0;
    __syncthreads();
    int cnt = min(bcount[b], CAP);
    for (int i = t; i < cnt; i += 256) {
        unsigned kk = pool[(size_t)b * CAP + i];
        int dl = (kk >> 16) & 31;
        int slot = atomicAdd(&dcnt[dl], 1);
        if (slot < BIN) s_src[dl][slot] = (unsigned short)kk;
    }
    __syncthreads();

    int ng = t >> 4;           // node group 0..15
    int l8 = t & 15;           // lane within node
    int c8 = l8 << 3;          // 8 channels per lane
    float nsig2 = -sigma[l8 >> 2] * 1.4426950408889634f;   // -sigma * log2(e)

    int nodeA = (b << 5) + ng;
    int nodeB = nodeA + 16;
    bool vA = nodeA < n, vB = nodeB < n;
    int degA = vA ? min(dcnt[ng], BIN) : 0;
    int degB = vB ? min(dcnt[ng + 16], BIN) : 0;

    // negated base pairs: nb[i] = -(ft_dst[2i..2i+1] + mu[2i..2i+1])
    f32x2 nbA[4], nbB[4];
    {
        const f32x2* mup = (const f32x2*)(mu + c8);
        uint4 dA = make_uint4(0u, 0u, 0u, 0u), dB = make_uint4(0u, 0u, 0u, 0u);
        if (vA) dA = *(const uint4*)(ftb + (size_t)nodeA * 128 + c8);
        if (vB) dB = *(const uint4*)(ftb + (size_t)nodeB * 128 + c8);
        nbA[0] = -pk_add(b2f2(dA.x), mup[0]); nbA[1] = -pk_add(b2f2(dA.y), mup[1]);
        nbA[2] = -pk_add(b2f2(dA.z), mup[2]); nbA[3] = -pk_add(b2f2(dA.w), mup[3]);
        nbB[0] = -pk_add(b2f2(dB.x), mup[0]); nbB[1] = -pk_add(b2f2(dB.y), mup[1]);
        nbB[2] = -pk_add(b2f2(dB.z), mup[2]); nbB[3] = -pk_add(b2f2(dB.w), mup[3]);
    }

    f32x2 accA[4] = {}, accB[4] = {};
    float denA = 0.f, denB = 0.f;
    const unsigned short* rowA = &s_src[ng][0];
    const unsigned short* rowB = &s_src[ng + 16][0];
    int jmax = max(degA, degB);

    for (int j = 0; j < jmax; j += 4) {
        ushort4 sa = *(const ushort4*)(rowA + j);
        ushort4 sb = *(const ushort4*)(rowB + j);
        uint4 a0 = *(const uint4*)(ftb + (((unsigned)sa.x << 7) + c8));
        uint4 a1 = *(const uint4*)(ftb + (((unsigned)sa.y << 7) + c8));
        uint4 a2 = *(const uint4*)(ftb + (((unsigned)sa.z << 7) + c8));
        uint4 a3 = *(const uint4*)(ftb + (((unsigned)sa.w << 7) + c8));
        uint4 b0 = *(const uint4*)(ftb + (((unsigned)sb.x << 7) + c8));
        uint4 b1 = *(const uint4*)(ftb + (((unsigned)sb.y << 7) + c8));
        uint4 b2 = *(const uint4*)(ftb + (((unsigned)sb.z << 7) + c8));
        uint4 b3 = *(const uint4*)(ftb + (((unsigned)sb.w << 7) + c8));
        // keep all 8 gathers issued before any consume (round-8: scheduler sinks
        // loads to save VGPRs, serializing the memory pipeline)
        __builtin_amdgcn_sched_barrier(0);
        consume4pk(a0, a1, a2, a3, nbA, nsig2, accA, denA);
        consume4pk(b0, b1, b2, b3, nbB, nsig2, accB, denB);
    }

    const float* bip = bias + c8;
    if (vA) {
        float inv = (degA > 0) ? 1.0f / denA : 0.f;
        float4 o0, o1;
        o0.x = fmaf(accA[0][0], inv, bip[0]); o0.y = fmaf(accA[0][1], inv, bip[1]);
        o0.z = fmaf(accA[1][0], inv, bip[2]); o0.w = fmaf(accA[1][1], inv, bip[3]);
        o1.x = fmaf(accA[2][0], inv, bip[4]); o1.y = fmaf(accA[2][1], inv, bip[5]);
        o1.z = fmaf(accA[3][0], inv, bip[6]); o1.w = fmaf(accA[3][1], inv, bip[7]);
        *(float4*)(out + (size_t)nodeA * 128 + c8) = o0;
        *(float4*)(out + (size_t)nodeA * 128 + c8 + 4) = o1;
    }
    if (vB) {
        float inv = (degB > 0) ? 1.0f / denB : 0.f;
        float4 o0, o1;
        o0.x = fmaf(accB[0][0], inv, bip[0]); o0.y = fmaf(accB[0][1], inv, bip[1]);
        o0.z = fmaf(accB[1][0], inv, bip[2]); o0.w = fmaf(accB[1][1], inv, bip[3]);
        o1.x = fmaf(accB[2][0], inv, bip[4]); o1.y = fmaf(accB[2][1], inv, bip[5]);
        o1.z = fmaf(accB[3][0], inv, bip[6]); o1.w = fmaf(accB[3][1], inv, bip[7]);
        *(float4*)(out + (size_t)nodeB * 128 + c8) = o0;
        *(float4*)(out + (size_t)nodeB * 128 + c8 + 4) = o1;
    }
}

extern "C" void kernel_launch(void* const* d_in, const int* in_sizes, int n_in,
                              void* d_out, int out_size, void* d_ws, size_t ws_size,
                              hipStream_t stream) {
    const float* feat  = (const float*)d_in[0];
    const float* W     = (const float*)d_in[1];
    const float* bias  = (const float*)d_in[2];
    const float* mu    = (const float*)d_in[3];
    const float* sigma = (const float*)d_in[4];
    const int*   src   = (const int*)d_in[5];
    const int*   dst   = (const int*)d_in[6];
    float* out = (float*)d_out;

    // workspace layout (~17.3 MB)
    unsigned short* ftb = (unsigned short*)d_ws;            // 50001*128 bf16 = 12.8 MB
    unsigned short* Wb  = ftb + (size_t)NROWS * 128;        // 16384 bf16
    int* bcount = (int*)(Wb + 16384);                       // 2048 ints
    unsigned* pool = (unsigned*)(bcount + NB_POW);          // 1563*704 u32 = 4.4 MB

    prep<<<25, 256, 0, stream>>>(W, Wb, bcount, ftb);
    produce<<<SC_BLOCKS + GEMM_BLOCKS, 256, 0, stream>>>(feat, Wb, ftb, src, dst,
                                                         bcount, pool, N_NODES);
    fused_node<<<NBUCKET, 256, 0, stream>>>(ftb, mu, sigma, bcount, pool,
                                            bias, out, N_NODES);
}

// Round 5
// 142.751 us; speedup vs baseline: 1.4248x; 1.4248x over previous
//
#include <hip/hip_runtime.h>
#include <math.h>

// GAUSConv: ft = bf16(feat@W.T) via MFMA -> bucket-radix edge pass -> per-bucket
// fused gaussian-softmax-reduce (softmax identity: out = sum(w*ft_src)/sum(w) + bias).
// Round-12: revert round-11's __launch_bounds__(256,8) on fused_node.
//   Counters showed it forced VGPR 60->32 and spilled the gather fragments to
//   scratch (WRITE_SIZE 25->147MB, FETCH 79->215MB, dur 41->96us). At VGPR=60
//   the HW already allows 8 blocks/CU (<=64-VGPR step) -- occupancy was never
//   the binding term. fused_node body = round-10 exactly, (256,4).
//   KEPT: produce's LDS-staged coalesced ftb epilogue (unattributed in r11;
//   total vs 143.7us baseline attributes it this round).
// N=50000, E=800000, D=128, K=4, F=32 (K*F = 128 = D)
#define N_NODES 50000
#define NROWS   50001          // +1 sentinel row (index 50000)
#define DUMMY   50000
#define N_EDGES 800000
#define NBUCKET 1563           // ceil(50000/32) coarse buckets, dst>>5
#define NB_POW  2048           // counter array size (pow2 >= NBUCKET)
#define CAP     704            // per-bucket pool capacity (mean 512, +8 sigma)
#define BIN     64             // per-dst cap; max in-degree ~35 for Poisson(16)
#define SPAD    72             // s_src row stride (u16): 144B, 16B-aligned rows
#define TSTR    132            // GEMM LDS tile row stride (u16): quad bank sets disjoint
#define SC_BLOCKS 196          // ceil(800000/4096) scatter blocks, 4096 edges each
#define GEMM_BLOCKS 782        // 64 rows each
#define SENT 0xFFFFFFFFu
#define DPAT 0xC350C350u       // u16 pattern = 50000 (sentinel)
#define DVAL 0x4E6Eu           // bf16 ~9.96e8: q ~ 3e19, sqrt ~ 5.6e9, w = 0 exactly

typedef __attribute__((ext_vector_type(8))) short bf16x8;
typedef __attribute__((ext_vector_type(4))) float f32x4;
typedef __attribute__((ext_vector_type(2))) float f32x2;

__device__ __forceinline__ unsigned short f2b(float f) {   // fp32 -> bf16 bits, RNE
    union { float f; unsigned u; } v; v.f = f;
    return (unsigned short)((v.u + 0x7FFFu + ((v.u >> 16) & 1u)) >> 16);
}
__device__ __forceinline__ float b2f_lo(unsigned u) {
    union { unsigned u; float f; } v; v.u = u << 16; return v.f;
}
__device__ __forceinline__ float b2f_hi(unsigned u) {
    union { unsigned u; float f; } v; v.u = u & 0xFFFF0000u; return v.f;
}
// decode a dword (2 bf16) into a packed f32 pair {lo_ch, hi_ch}
__device__ __forceinline__ f32x2 b2f2(unsigned u) {
    f32x2 r; r[0] = b2f_lo(u); r[1] = b2f_hi(u); return r;
}
// VOP3P packed f32 math (2 FMAs / 2 ADDs per instruction)
__device__ __forceinline__ f32x2 pk_fma(f32x2 a, f32x2 b, f32x2 c) {
    f32x2 d;
    asm("v_pk_fma_f32 %0, %1, %2, %3" : "=v"(d) : "v"(a), "v"(b), "v"(c));
    return d;
}
__device__ __forceinline__ f32x2 pk_add(f32x2 a, f32x2 b) {
    f32x2 d;
    asm("v_pk_add_f32 %0, %1, %2" : "=v"(d) : "v"(a), "v"(b));
    return d;
}
// q += quad-lane butterfly via DPP (no LDS pipe)
#define DPP_ADD(q, CTRL) { \
    int _r = __builtin_amdgcn_update_dpp(0, __builtin_bit_cast(int, q), CTRL, 0xF, 0xF, false); \
    q += __builtin_bit_cast(float, _r); }

#if __has_builtin(__builtin_amdgcn_exp2f)
#define EXP2F(x) __builtin_amdgcn_exp2f(x)
#else
#define EXP2F(x) exp2f(x)
#endif

// ---------------- prep: W -> bf16 + zero bucket counters + sentinel ft row ----------
__global__ __launch_bounds__(256) void prep(const float* __restrict__ W,
                                            unsigned short* __restrict__ Wb,
                                            int* __restrict__ bcount,
                                            unsigned short* __restrict__ ftb) {
    int idx = blockIdx.x * 256 + threadIdx.x;
    if (idx < 4096) {
        int i = idx * 4;
        float4 v = *(const float4*)(W + i);
        Wb[i + 0] = f2b(v.x); Wb[i + 1] = f2b(v.y);
        Wb[i + 2] = f2b(v.z); Wb[i + 3] = f2b(v.w);
    } else if (idx < 4096 + NB_POW) {
        bcount[idx - 4096] = 0;
    } else if (idx < 4096 + NB_POW + 32) {
        int i = (idx - 4096 - NB_POW) * 4;
        unsigned short* p = ftb + (size_t)DUMMY * 128 + i;
        p[0] = DVAL; p[1] = DVAL; p[2] = DVAL; p[3] = DVAL;
    }
}

// ---------------- produce: [0,SC) bucket scatter || [SC,SC+GEMM) MFMA GEMM ----------
__global__ __launch_bounds__(256) void produce(const float* __restrict__ feat,
                                               const unsigned short* __restrict__ Wb,
                                               unsigned short* __restrict__ ftb,
                                               const int* __restrict__ src,
                                               const int* __restrict__ dst,
                                               int* __restrict__ bcount,
                                               unsigned* __restrict__ pool, int n) {
    __shared__ int smem[3 * NB_POW];     // 24 KB, overlaid: scatter hist | GEMM tile
    if (blockIdx.x < SC_BLOCKS) {
        int* hist = smem;
        int* gbase = smem + NB_POW;
        int* cur = smem + 2 * NB_POW;
        int t = threadIdx.x;
        #pragma unroll
        for (int i = 0; i < NB_POW / 256; ++i) hist[t + i * 256] = 0;
        __syncthreads();

        unsigned key[16];
        int ebase = blockIdx.x * 4096 + (t << 2);
        #pragma unroll
        for (int i = 0; i < 4; ++i) {
            int e = ebase + i * 1024;
            if (e + 3 < N_EDGES) {
                int4 s4 = *(const int4*)(src + e);
                int4 d4 = *(const int4*)(dst + e);
                key[i * 4 + 0] = ((unsigned)d4.x << 16) | (unsigned)s4.x;
                key[i * 4 + 1] = ((unsigned)d4.y << 16) | (unsigned)s4.y;
                key[i * 4 + 2] = ((unsigned)d4.z << 16) | (unsigned)s4.z;
                key[i * 4 + 3] = ((unsigned)d4.w << 16) | (unsigned)s4.w;
            } else {
                #pragma unroll
                for (int j = 0; j < 4; ++j) {
                    int ee = e + j;
                    key[i * 4 + j] = (ee < N_EDGES)
                        ? (((unsigned)dst[ee] << 16) | (unsigned)src[ee]) : SENT;
                }
            }
        }
        #pragma unroll
        for (int i = 0; i < 16; ++i)
            if (key[i] != SENT) atomicAdd(&hist[key[i] >> 21], 1);
        __syncthreads();
        #pragma unroll
        for (int i = 0; i < NB_POW / 256; ++i) {
            int b = t + i * 256;
            int h = hist[b];
            cur[b] = 0;
            gbase[b] = (h > 0) ? atomicAdd(&bcount[b], h) : 0;
        }
        __syncthreads();
        #pragma unroll
        for (int i = 0; i < 16; ++i) {
            unsigned kk = key[i];
            if (kk != SENT) {
                int b = kk >> 21;                     // dst>>5
                int pos = gbase[b] + atomicAdd(&cur[b], 1);
                if (pos < CAP) pool[(size_t)b * CAP + pos] = kk;
            }
        }
        return;
    }
    // ---- GEMM path ----
    int gb = blockIdx.x - SC_BLOCKS;
    int t = threadIdx.x;
    int wave = t >> 6, l = t & 63;
    int m = l & 15, quad = l >> 4;
    int row0 = gb * 64 + wave * 16;
    int grow = row0 + m;
    int arow = grow < n ? grow : (n - 1);
    f32x4 acc[8] = {};
    const float* ap = feat + (size_t)arow * 128 + quad * 8;
    #pragma unroll
    for (int ks = 0; ks < 4; ++ks) {
        float4 a0 = *(const float4*)(ap + ks * 32);
        float4 a1 = *(const float4*)(ap + ks * 32 + 4);
        bf16x8 af;
        af[0] = (short)f2b(a0.x); af[1] = (short)f2b(a0.y);
        af[2] = (short)f2b(a0.z); af[3] = (short)f2b(a0.w);
        af[4] = (short)f2b(a1.x); af[5] = (short)f2b(a1.y);
        af[6] = (short)f2b(a1.z); af[7] = (short)f2b(a1.w);
        #pragma unroll
        for (int ct = 0; ct < 8; ++ct) {
            int ncol = ct * 16 + m;
            bf16x8 bf = *(const bf16x8*)(Wb + (size_t)ncol * 128 + ks * 32 + quad * 8);
            acc[ct] = __builtin_amdgcn_mfma_f32_16x16x32_bf16(af, bf, acc[ct], 0, 0, 0);
        }
    }
    // stage tile in LDS (row stride 132 u16 -> quads hit disjoint bank sets),
    // then write ftb coalesced 16B (was: 32 scattered 2B stores per lane).
    unsigned short* tile = (unsigned short*)smem;   // 64*132*2 = 16.9 KB <= 24 KB
    #pragma unroll
    for (int r = 0; r < 4; ++r) {
        int trow = wave * 16 + quad * 4 + r;
        #pragma unroll
        for (int ct = 0; ct < 8; ++ct)
            tile[trow * TSTR + ct * 16 + m] = f2b(acc[ct][r]);
    }
    __syncthreads();
    #pragma unroll
    for (int it = 0; it < 4; ++it) {
        int elem = (t + it * 256) * 8;   // < 8192
        int row = elem >> 7;
        int col = elem & 127;
        int gr = gb * 64 + row;
        if (gr < n) {
            const unsigned short* tp = tile + row * TSTR + col;
            uint2 lo = *(const uint2*)tp;
            uint2 hi = *(const uint2*)(tp + 4);
            uint4 v = make_uint4(lo.x, lo.y, hi.x, hi.y);
            *(uint4*)(ftb + (size_t)gr * 128 + col) = v;
        }
    }
}

// ---------------- fused: bucket LDS binning + gaussian-softmax-reduce ----------
// consume 4 edges, packed-f32 math, DPP reduce, no masks (sentinel rows -> w=0).
__device__ __forceinline__ void consume4pk(uint4 r0, uint4 r1, uint4 r2, uint4 r3,
                                           const f32x2* nb, float nsig2,
                                           f32x2* acc, float& den) {
    #define EDGE(R) { \
        f32x2 f0 = b2f2(R.x), f1 = b2f2(R.y), f2 = b2f2(R.z), f3 = b2f2(R.w); \
        f32x2 d0 = pk_add(f0, nb[0]), d1 = pk_add(f1, nb[1]); \
        f32x2 d2 = pk_add(f2, nb[2]), d3 = pk_add(f3, nb[3]); \
        f32x2 q2 = pk_fma(d0, d0, pk_fma(d1, d1, pk_fma(d2, d2, pk_fma(d3, d3, (f32x2)(0.f))))); \
        float q = q2[0] + q2[1]; \
        DPP_ADD(q, 0xB1) \
        DPP_ADD(q, 0x4E) \
        float w = EXP2F(nsig2 * __builtin_amdgcn_sqrtf(q)); \
        f32x2 w2; w2[0] = w; w2[1] = w; \
        acc[0] = pk_fma(f0, w2, acc[0]); acc[1] = pk_fma(f1, w2, acc[1]); \
        acc[2] = pk_fma(f2, w2, acc[2]); acc[3] = pk_fma(f3, w2, acc[3]); \
        den += w; }
    EDGE(r0) EDGE(r1) EDGE(r2) EDGE(r3)
    #undef EDGE
}

__global__ __launch_bounds__(256, 4) void fused_node(const unsigned short* __restrict__ ftb,
                                                     const float* __restrict__ mu,
                                                     const float* __restrict__ sigma,
                                                     const int* __restrict__ bcount,
                                                     const unsigned* __restrict__ pool,
                                                     const float* __restrict__ bias,
                                                     float* __restrict__ out, int n) {
    __shared__ __align__(16) unsigned short s_src[32][SPAD];   // 4608 B
    __shared__ int dcnt[32];
    int t = threadIdx.x;
    int b = blockIdx.x;
    {   // sentinel-fill: unused slots gather the dummy row -> w = 0, no masking
        uint4* p = (uint4*)&s_src[0][0];
        const uint4 DP = make_uint4(DPAT, DPAT, DPAT, DPAT);
        for (int i = t; i < 32 * SPAD * 2 / 16; i += 256) p[i] = DP;
    }
    if (t < 32) dcnt[t] = 0;
    __syncthreads();
    int cnt = min(bcount[b], CAP);
    for (int i = t; i < cnt; i += 256) {
        unsigned kk = pool[(size_t)b * CAP + i];
        int dl = (kk >> 16) & 31;
        int slot = atomicAdd(&dcnt[dl], 1);
        if (slot < BIN) s_src[dl][slot] = (unsigned short)kk;
    }
    __syncthreads();

    int ng = t >> 4;           // node group 0..15
    int l8 = t & 15;           // lane within node
    int c8 = l8 << 3;          // 8 channels per lane
    float nsig2 = -sigma[l8 >> 2] * 1.4426950408889634f;   // -sigma * log2(e)

    int nodeA = (b << 5) + ng;
    int nodeB = nodeA + 16;
    bool vA = nodeA < n, vB = nodeB < n;
    int degA = vA ? min(dcnt[ng], BIN) : 0;
    int degB = vB ? min(dcnt[ng + 16], BIN) : 0;

    // negated base pairs: nb[i] = -(ft_dst[2i..2i+1] + mu[2i..2i+1])
    f32x2 nbA[4], nbB[4];
    {
        const f32x2* mup = (const f32x2*)(mu + c8);
        uint4 dA = make_uint4(0u, 0u, 0u, 0u), dB = make_uint4(0u, 0u, 0u, 0u);
        if (vA) dA = *(const uint4*)(ftb + (size_t)nodeA * 128 + c8);
        if (vB) dB = *(const uint4*)(ftb + (size_t)nodeB * 128 + c8);
        nbA[0] = -pk_add(b2f2(dA.x), mup[0]); nbA[1] = -pk_add(b2f2(dA.y), mup[1]);
        nbA[2] = -pk_add(b2f2(dA.z), mup[2]); nbA[3] = -pk_add(b2f2(dA.w), mup[3]);
        nbB[0] = -pk_add(b2f2(dB.x), mup[0]); nbB[1] = -pk_add(b2f2(dB.y), mup[1]);
        nbB[2] = -pk_add(b2f2(dB.z), mup[2]); nbB[3] = -pk_add(b2f2(dB.w), mup[3]);
    }

    f32x2 accA[4] = {}, accB[4] = {};
    float denA = 0.f, denB = 0.f;
    const unsigned short* rowA = &s_src[ng][0];
    const unsigned short* rowB = &s_src[ng + 16][0];
    int jmax = max(degA, degB);

    for (int j = 0; j < jmax; j += 4) {
        ushort4 sa = *(const ushort4*)(rowA + j);
        ushort4 sb = *(const ushort4*)(rowB + j);
        uint4 a0 = *(const uint4*)(ftb + (((unsigned)sa.x << 7) + c8));
        uint4 a1 = *(const uint4*)(ftb + (((unsigned)sa.y << 7) + c8));
        uint4 a2 = *(const uint4*)(ftb + (((unsigned)sa.z << 7) + c8));
        uint4 a3 = *(const uint4*)(ftb + (((unsigned)sa.w << 7) + c8));
        uint4 b0 = *(const uint4*)(ftb + (((unsigned)sb.x << 7) + c8));
        uint4 b1 = *(const uint4*)(ftb + (((unsigned)sb.y << 7) + c8));
        uint4 b2 = *(const uint4*)(ftb + (((unsigned)sb.z << 7) + c8));
        uint4 b3 = *(const uint4*)(ftb + (((unsigned)sb.w << 7) + c8));
        // keep all 8 gathers issued before any consume (round-8: scheduler sinks
        // loads to save VGPRs, serializing the memory pipeline)
        __builtin_amdgcn_sched_barrier(0);
        consume4pk(a0, a1, a2, a3, nbA, nsig2, accA, denA);
        consume4pk(b0, b1, b2, b3, nbB, nsig2, accB, denB);
    }

    const float* bip = bias + c8;
    if (vA) {
        float inv = (degA > 0) ? 1.0f / denA : 0.f;
        float4 o0, o1;
        o0.x = fmaf(accA[0][0], inv, bip[0]); o0.y = fmaf(accA[0][1], inv, bip[1]);
        o0.z = fmaf(accA[1][0], inv, bip[2]); o0.w = fmaf(accA[1][1], inv, bip[3]);
        o1.x = fmaf(accA[2][0], inv, bip[4]); o1.y = fmaf(accA[2][1], inv, bip[5]);
        o1.z = fmaf(accA[3][0], inv, bip[6]); o1.w = fmaf(accA[3][1], inv, bip[7]);
        *(float4*)(out + (size_t)nodeA * 128 + c8) = o0;
        *(float4*)(out + (size_t)nodeA * 128 + c8 + 4) = o1;
    }
    if (vB) {
        float inv = (degB > 0) ? 1.0f / denB : 0.f;
        float4 o0, o1;
        o0.x = fmaf(accB[0][0], inv, bip[0]); o0.y = fmaf(accB[0][1], inv, bip[1]);
        o0.z = fmaf(accB[1][0], inv, bip[2]); o0.w = fmaf(accB[1][1], inv, bip[3]);
        o1.x = fmaf(accB[2][0], inv, bip[4]); o1.y = fmaf(accB[2][1], inv, bip[5]);
        o1.z = fmaf(accB[3][0], inv, bip[6]); o1.w = fmaf(accB[3][1], inv, bip[7]);
        *(float4*)(out + (size_t)nodeB * 128 + c8) = o0;
        *(float4*)(out + (size_t)nodeB * 128 + c8 + 4) = o1;
    }
}

extern "C" void kernel_launch(void* const* d_in, const int* in_sizes, int n_in,
                              void* d_out, int out_size, void* d_ws, size_t ws_size,
                              hipStream_t stream) {
    const float* feat  = (const float*)d_in[0];
    const float* W     = (const float*)d_in[1];
    const float* bias  = (const float*)d_in[2];
    const float* mu    = (const float*)d_in[3];
    const float* sigma = (const float*)d_in[4];
    const int*   src   = (const int*)d_in[5];
    const int*   dst   = (const int*)d_in[6];
    float* out = (float*)d_out;

    // workspace layout (~17.3 MB)
    unsigned short* ftb = (unsigned short*)d_ws;            // 50001*128 bf16 = 12.8 MB
    unsigned short* Wb  = ftb + (size_t)NROWS * 128;        // 16384 bf16
    int* bcount = (int*)(Wb + 16384);                       // 2048 ints
    unsigned* pool = (unsigned*)(bcount + NB_POW);          // 1563*704 u32 = 4.4 MB

    prep<<<25, 256, 0, stream>>>(W, Wb, bcount, ftb);
    produce<<<SC_BLOCKS + GEMM_BLOCKS, 256, 0, stream>>>(feat, Wb, ftb, src, dst,
                                                         bcount, pool, N_NODES);
    fused_node<<<NBUCKET, 256, 0, stream>>>(ftb, mu, sigma, bcount, pool,
                                            bias, out, N_NODES);
}